// Round 2
// baseline (5552.546 us; speedup 1.0000x reference)
//
#include <hip/hip_runtime.h>

// ---------------------------------------------------------------------------
// 2-layer tanh RNN, B=64, T=512, I=256, H=512.  Round 7: sentinel-poll
// dataflow -- zero flags, zero drains on the critical path.
//   - h slabs pre-filled with 0xFFFFFFFF (fp16 NaN|NaN).  tanh outputs are
//     never NaN, so "dword != -1" == "data arrived".  Producers store tiles
//     write-through (sc0 sc1) and never wait; consumers poll their own MFMA
//     A-fragments with L1/L2-bypassing loads until clean -- notify and data
//     are ONE LLC transaction.
//   - 512-thr blocks (2 waves/SIMD -> 256 VGPR cap): weights stay genuinely
//     register-resident (fp16, pre-converted).
//   - layer0: 4 groups x 2 halves; wave owns 32 cols full-K (128 VGPR of
//     W_hh0).  Own half of h(t) from double-buffered LDS; peer half polled;
//     own-half MFMAs overlap the poll flight.  ONE barrier per step.
//   - layer1: 4 groups x 4 quarters; wave owns 16 cols of BOTH W_ih1/W_hh1
//     (128 VGPR).  Gate A: peer h1(t) poll (usually ready); gate B:
//     out0(t+1) poll (the fresh dependency).
//   - all tile stores coalesced through swizzled LDS (16B/lane).
// ---------------------------------------------------------------------------

#define kB 64
#define kT 512
#define kI 256
#define kH 512
#define kBH (kB * kH)   // 32768

typedef _Float16 half8 __attribute__((ext_vector_type(8)));
typedef float floatx4 __attribute__((ext_vector_type(4)));
typedef unsigned u32x4 __attribute__((ext_vector_type(4)));
typedef unsigned u32x2 __attribute__((ext_vector_type(2)));

#define MFMA(a, b, c) __builtin_amdgcn_mfma_f32_16x16x32_f16(a, b, c, 0, 0, 0)

// ws layout (bytes)
constexpr size_t W16_B   = 0;                      // wih0 fp16, 256 KB
constexpr size_t WH0_B   = 256u * 1024;            // whh0 fp16, 512 KB
constexpr size_t WI1_B   = WH0_B + 512u * 1024;    // wih1 fp16, 512 KB
constexpr size_t WH1_B   = WI1_B + 512u * 1024;    // whh1 fp16, 512 KB
constexpr size_t OUT0M_B = 2u * 1024 * 1024;                      // [T+1][B][H] fp16
constexpr size_t H1M_B   = OUT0M_B + (size_t)(kT + 1) * kBH * 2;  // [T+1][B][H] fp16

__device__ inline void llc_store16(void* p, u32x4 v) {
    asm volatile("global_store_dwordx4 %0, %1, off sc0 sc1" :: "v"(p), "v"(v) : "memory");
}
__device__ inline void llc_store8(void* p, u32x2 v) {
    asm volatile("global_store_dwordx2 %0, %1, off sc0 sc1" :: "v"(p), "v"(v) : "memory");
}
#define LLC_ISSUE16(dst, p) \
    asm volatile("global_load_dwordx4 %0, %1, off sc0 sc1" : "=v"(dst) : "v"(p))

__device__ inline unsigned dirty4(u32x4 v) {
    unsigned m01 = v[0] > v[1] ? v[0] : v[1];
    unsigned m23 = v[2] > v[3] ? v[2] : v[3];
    unsigned m = m01 > m23 ? m01 : m23;
    return m == 0xFFFFFFFFu;   // any dword still the sentinel
}

__device__ inline float fast_tanh(float x) {
    float e = __expf(2.f * x);
    return 1.f - 2.f / (e + 1.f);   // exact +-1 saturation, no NaN
}

// ---------------------------------------------------------------------------
__global__ void setup_kernel(const float* __restrict__ h0,
                             const float* __restrict__ wih0, const float* __restrict__ whh0,
                             const float* __restrict__ wih1, const float* __restrict__ whh1,
                             _Float16* __restrict__ w16, _Float16* __restrict__ wh0_16,
                             _Float16* __restrict__ wi1_16, _Float16* __restrict__ wh1_16,
                             _Float16* __restrict__ out0m, _Float16* __restrict__ h1m) {
    size_t tid = (size_t)blockIdx.x * blockDim.x + threadIdx.x;
    size_t stride = (size_t)gridDim.x * blockDim.x;
    for (size_t i = tid; i < (size_t)kH * kI; i += stride) w16[i] = (_Float16)wih0[i];
    for (size_t i = tid; i < (size_t)kH * kH; i += stride) {
        wh0_16[i] = (_Float16)whh0[i];
        wi1_16[i] = (_Float16)wih1[i];
        wh1_16[i] = (_Float16)whh1[i];
    }
    for (size_t i = tid; i < kBH; i += stride) {
        out0m[i] = (_Float16)h0[i];
        h1m[i]   = (_Float16)h0[kBH + i];
    }
    // sentinel-fill slabs 1..T of both h arrays
    u32x4 s = {0xFFFFFFFFu, 0xFFFFFFFFu, 0xFFFFFFFFu, 0xFFFFFFFFu};
    u32x4* a = (u32x4*)(out0m + kBH);
    u32x4* b = (u32x4*)(h1m + kBH);
    const size_t nf = (size_t)kT * kBH / 8;
    for (size_t i = tid; i < nf; i += stride) { a[i] = s; b[i] = s; }
}

__device__ inline half8 cvt8(const float* p) {
    const float4* p4 = (const float4*)p;
    float4 a = p4[0], b = p4[1];
    half8 h;
    h[0] = (_Float16)a.x; h[1] = (_Float16)a.y; h[2] = (_Float16)a.z; h[3] = (_Float16)a.w;
    h[4] = (_Float16)b.x; h[5] = (_Float16)b.y; h[6] = (_Float16)b.z; h[7] = (_Float16)b.w;
    return h;
}

// xw[b][t][c] = sum_i x[b,t,i]*Wih0[c,i] + bih0[c] + bhh0[c]   (fp32, into d_out)
__global__ __launch_bounds__(256) void xw_kernel(
    const float* __restrict__ x, const _Float16* __restrict__ w16,
    const float* __restrict__ bih, const float* __restrict__ bhh, float* xw) {
    const int mb = blockIdx.x >> 3, nb = blockIdx.x & 7;
    const int wave = threadIdx.x >> 6, lane = threadIdx.x & 63;
    const int r = lane & 15, q = lane >> 4;
    const int m0 = mb * 64 + wave * 16;
    half8 a[8];
#pragma unroll
    for (int ko = 0; ko < 8; ++ko)
        a[ko] = cvt8(x + (size_t)(m0 + r) * kI + ko * 32 + q * 8);
#pragma unroll
    for (int ct = 0; ct < 4; ++ct) {
        const int cc = nb * 64 + ct * 16 + r;
        const float bias = bih[cc] + bhh[cc];
        floatx4 acc = {bias, bias, bias, bias};
#pragma unroll
        for (int ko = 0; ko < 8; ++ko) {
            half8 b = *(const half8*)(w16 + (size_t)cc * kI + ko * 32 + q * 8);
            acc = MFMA(a[ko], b, acc);
        }
#pragma unroll
        for (int j = 0; j < 4; ++j)
            xw[(size_t)(m0 + q * 4 + j) * kH + cc] = acc[j];
    }
}

// ---------------------------------------------------------------------------
__global__ __launch_bounds__(512, 2) void scan_kernel(
    const float* xw,                       // = d_out (fp32 [B][T][H]), layer0 reads
    _Float16* __restrict__ out0m, _Float16* __restrict__ h1m,
    float* out1,                           // = d_out, layer1 writes
    const _Float16* __restrict__ wh0_16,
    const _Float16* __restrict__ wi1_16, const _Float16* __restrict__ wh1_16,
    const float* __restrict__ bih1, const float* __restrict__ bhh1) {
    __shared__ __align__(16) char smem[24576];

    const int blk = blockIdx.x;
    const int tid = threadIdx.x;
    const int wave = tid >> 6, lane = tid & 63;
    const int r = lane & 15, q = lane >> 4;
    const int swzr = (r & 7) << 4;
    const int srow = tid >> 5, sl32 = tid & 31;      // coalesce-store mapping
    const int swzs = (srow & 7) << 4;

    if (blk < 8) {
        // ---------------- layer 0: 4 groups x 2 col-halves ----------------
        const int g = blk >> 1, half = blk & 1;
        const int b0 = g * 16;
        const int cb = half * 256 + wave * 32;       // global col base (32 cols/wave)
        half8 wf0[16], wf1[16];
#pragma unroll
        for (int ks = 0; ks < 16; ++ks) {
            wf0[ks] = *(const half8*)(wh0_16 + (size_t)(cb + r) * kH + ks * 32 + q * 8);
            wf1[ks] = *(const half8*)(wh0_16 + (size_t)(cb + 16 + r) * kH + ks * 32 + q * 8);
        }
        // stage own half of h(0) into LDS buf0
        {
            u32x4 v = *(const u32x4*)(out0m + (size_t)(b0 + srow) * kH + half * 256 + sl32 * 8);
            *(u32x4*)(smem + srow * 512 + ((sl32 * 16) ^ swzs)) = v;
        }
        __syncthreads();

        for (int t = 0; t < kT; ++t) {
            char* bufR = smem + (t & 1) * 8192;
            char* bufW = smem + ((t + 1) & 1) * 8192;
            // xw prefetch (epilogue-only use)
            float xv0[4], xv1[4];
#pragma unroll
            for (int j = 0; j < 4; ++j) {
                const size_t rowb = ((size_t)(b0 + q * 4 + j) * kT + t) * kH;
                xv0[j] = xw[rowb + cb + r];
                xv1[j] = xw[rowb + cb + 16 + r];
            }
            // issue peer-half polls (8 x 16B = this lane's A-fragments)
            u32x4 ph[8];
            const _Float16* pb = out0m + (size_t)t * kBH + (size_t)(b0 + r) * kH
                                 + (half ^ 1) * 256 + q * 8;
#pragma unroll
            for (int i = 0; i < 8; ++i) LLC_ISSUE16(ph[i], pb + i * 32);
            // own-half A-frags from LDS + MFMAs (overlap the poll flight)
            floatx4 a0 = {0.f, 0.f, 0.f, 0.f}, a1 = {0.f, 0.f, 0.f, 0.f};
#pragma unroll
            for (int i = 0; i < 8; ++i) {
                half8 la = *(const half8*)(bufR + r * 512 + ((i * 64 + q * 16) ^ swzr));
                a0 = MFMA(la, wf0[half * 8 + i], a0);
                a1 = MFMA(la, wf1[half * 8 + i], a1);
            }
            // poll until clean
            {
                int guard = 0;
                for (;;) {
                    __builtin_amdgcn_s_waitcnt(0x0F70);   // vmcnt(0)
                    __builtin_amdgcn_sched_barrier(0);
                    unsigned d = 0;
#pragma unroll
                    for (int i = 0; i < 8; ++i) d |= dirty4(ph[i]);
                    if (!__any(d != 0)) break;
                    if (++guard > (1 << 20)) break;       // fail-wrong, not hang
#pragma unroll
                    for (int i = 0; i < 8; ++i) LLC_ISSUE16(ph[i], pb + i * 32);
                }
            }
            // peer-half MFMAs
#pragma unroll
            for (int i = 0; i < 8; ++i) {
                half8 pa = __builtin_bit_cast(half8, ph[i]);
                a0 = MFMA(pa, wf0[(half ^ 1) * 8 + i], a0);
                a1 = MFMA(pa, wf1[(half ^ 1) * 8 + i], a1);
            }
            // epilogue -> LDS (next step's A source)
#pragma unroll
            for (int j = 0; j < 4; ++j) {
                float v0 = fast_tanh(a0[j] + xv0[j]);
                float v1 = fast_tanh(a1[j] + xv1[j]);
                const int row = q * 4 + j;
                const int sz = (row & 7) << 4;
                *(_Float16*)(bufW + row * 512 + (((wave * 32 + r) * 2) ^ sz)) = (_Float16)v0;
                *(_Float16*)(bufW + row * 512 + (((wave * 32 + 16 + r) * 2) ^ sz)) = (_Float16)v1;
            }
            __syncthreads();
            // coalesced write-through tile store (data IS the notification)
            u32x4 sv = *(const u32x4*)(bufW + srow * 512 + ((sl32 * 16) ^ swzs));
            llc_store16(out0m + (size_t)(t + 1) * kBH + (size_t)(b0 + srow) * kH
                        + half * 256 + sl32 * 8, sv);
        }
    } else {
        // ---------------- layer 1: 4 groups x 4 col-quarters ----------------
        const int b2 = blk - 8;
        const int g = b2 >> 2, qb = b2 & 3;
        const int b0 = g * 16;
        const int c0 = qb * 128 + wave * 16;         // global col base (16 cols/wave)
        half8 wfh[16], wfi[16];
#pragma unroll
        for (int ks = 0; ks < 16; ++ks) {
            wfh[ks] = *(const half8*)(wh1_16 + (size_t)(c0 + r) * kH + ks * 32 + q * 8);
            wfi[ks] = *(const half8*)(wi1_16 + (size_t)(c0 + r) * kH + ks * 32 + q * 8);
        }
        const float bias = bih1[c0 + r] + bhh1[c0 + r];
        char* h1b = smem;                            // [2][16][256B]
        char* o1b = smem + 8192;                     // [2][16][512B]
        // stage own quarter of h1(0)
        {
            u32x2 v = *(const u32x2*)(h1m + (size_t)(b0 + srow) * kH + qb * 128 + sl32 * 4);
            *(u32x2*)(h1b + srow * 256 + ((sl32 * 8) ^ swzs)) = v;
        }
        __syncthreads();

        for (int t = 0; t < kT; ++t) {
            char* bR = h1b + (t & 1) * 4096;
            char* bW = h1b + ((t + 1) & 1) * 4096;
            char* oW = o1b + (t & 1) * 8192;
            floatx4 a0 = {0.f, 0.f, 0.f, 0.f}, a1 = {0.f, 0.f, 0.f, 0.f};
            // gate A: peer quarters of h1(t) -- usually already arrived
            u32x4 hp[12];
            const _Float16* hb = h1m + (size_t)t * kBH + (size_t)(b0 + r) * kH + q * 8;
#pragma unroll
            for (int i = 0; i < 12; ++i) {
                const int ks = i + (i >= qb * 4 ? 4 : 0);
                LLC_ISSUE16(hp[i], hb + ks * 32);
            }
            // own quarter from LDS + MFMAs (overlap)
#pragma unroll
            for (int i = 0; i < 4; ++i) {
                half8 la = *(const half8*)(bR + r * 256 + ((i * 64 + q * 16) ^ swzr));
                a0 = MFMA(la, wfh[qb * 4 + i], a0);
            }
            {
                int guard = 0;
                for (;;) {
                    __builtin_amdgcn_s_waitcnt(0x0F70);
                    __builtin_amdgcn_sched_barrier(0);
                    unsigned d = 0;
#pragma unroll
                    for (int i = 0; i < 12; ++i) d |= dirty4(hp[i]);
                    if (!__any(d != 0)) break;
                    if (++guard > (1 << 20)) break;
#pragma unroll
                    for (int i = 0; i < 12; ++i) {
                        const int ks = i + (i >= qb * 4 ? 4 : 0);
                        LLC_ISSUE16(hp[i], hb + ks * 32);
                    }
                }
            }
#pragma unroll
            for (int i = 0; i < 12; ++i) {
                const int ks = i + (i >= qb * 4 ? 4 : 0);
                a0 = MFMA(__builtin_bit_cast(half8, hp[i]), wfh[ks], a0);
            }
            // gate B: out0(t+1) -- the fresh dependency
            u32x4 xp[16];
            const _Float16* xb = out0m + (size_t)(t + 1) * kBH + (size_t)(b0 + r) * kH + q * 8;
#pragma unroll
            for (int i = 0; i < 16; ++i) LLC_ISSUE16(xp[i], xb + i * 32);
            {
                int guard = 0;
                for (;;) {
                    __builtin_amdgcn_s_waitcnt(0x0F70);
                    __builtin_amdgcn_sched_barrier(0);
                    unsigned d = 0;
#pragma unroll
                    for (int i = 0; i < 16; ++i) d |= dirty4(xp[i]);
                    if (!__any(d != 0)) break;
                    if (++guard > (1 << 20)) break;
#pragma unroll
                    for (int i = 0; i < 16; ++i) LLC_ISSUE16(xp[i], xb + i * 32);
                }
            }
#pragma unroll
            for (int i = 0; i < 16; ++i)
                a1 = MFMA(__builtin_bit_cast(half8, xp[i]), wfi[i], a1);
            // epilogue
#pragma unroll
            for (int j = 0; j < 4; ++j) {
                float v = fast_tanh(a0[j] + a1[j] + bias);
                const int row = q * 4 + j;
                const int sz = (row & 7) << 4;
                const int cl = wave * 16 + r;
                *(_Float16*)(bW + row * 256 + ((cl * 2) ^ sz)) = (_Float16)v;
                *(float*)(oW + row * 512 + ((cl * 4) ^ sz)) = v;
            }
            __syncthreads();
            // coalesced stores: h1 tile write-through; out1 plain fp32
            u32x2 hv = *(const u32x2*)(bW + srow * 256 + ((sl32 * 8) ^ swzs));
            llc_store8(h1m + (size_t)(t + 1) * kBH + (size_t)(b0 + srow) * kH
                       + qb * 128 + sl32 * 4, hv);
            u32x4 ov = *(const u32x4*)(oW + srow * 512 + ((sl32 * 16) ^ swzs));
            *(u32x4*)(out1 + ((size_t)(b0 + srow) * kT + t) * kH + qb * 128 + sl32 * 4) = ov;
        }
    }
}

__global__ void finalize_kernel(const _Float16* __restrict__ out0m,
                                const _Float16* __restrict__ h1m,
                                float* __restrict__ out) {
    int idx = blockIdx.x * blockDim.x + threadIdx.x;  // 0 .. 65535
    float* hn = out + (size_t)kB * kT * kH;
    if (idx < kBH) hn[idx] = (float)out0m[(size_t)kT * kBH + idx];
    else hn[idx] = (float)h1m[(size_t)kT * kBH + (idx - kBH)];
}

extern "C" void kernel_launch(void* const* d_in, const int* in_sizes, int n_in,
                              void* d_out, int out_size, void* d_ws, size_t ws_size,
                              hipStream_t stream) {
    const float* x    = (const float*)d_in[0];
    const float* h0in = (const float*)d_in[1];
    const float* wih0 = (const float*)d_in[2];
    const float* whh0 = (const float*)d_in[3];
    const float* bih0 = (const float*)d_in[4];
    const float* bhh0 = (const float*)d_in[5];
    const float* wih1 = (const float*)d_in[6];
    const float* whh1 = (const float*)d_in[7];
    const float* bih1 = (const float*)d_in[8];
    const float* bhh1 = (const float*)d_in[9];
    float* out = (float*)d_out;
    char* ws = (char*)d_ws;

    _Float16* w16    = (_Float16*)(ws + W16_B);
    _Float16* wh0_16 = (_Float16*)(ws + WH0_B);
    _Float16* wi1_16 = (_Float16*)(ws + WI1_B);
    _Float16* wh1_16 = (_Float16*)(ws + WH1_B);
    _Float16* out0m  = (_Float16*)(ws + OUT0M_B);
    _Float16* h1m    = (_Float16*)(ws + H1M_B);

    setup_kernel<<<2048, 256, 0, stream>>>(h0in, wih0, whh0, wih1, whh1,
                                           w16, wh0_16, wi1_16, wh1_16, out0m, h1m);
    xw_kernel<<<4096, 256, 0, stream>>>(x, w16, bih0, bhh0, out);
    scan_kernel<<<24, 512, 0, stream>>>(out, out0m, h1m, out,
                                        wh0_16, wi1_16, wh1_16, bih1, bhh1);
    finalize_kernel<<<256, 256, 0, stream>>>(out0m, h1m, out);
}